// Round 4
// baseline (645.509 us; speedup 1.0000x reference)
//
#include <hip/hip_runtime.h>

// Problem constants
#define NAG 8
#define BB 32768
#define SDIM 128
#define ADIM 16
#define HID 128
#define IDIM 144

typedef unsigned short u16;
typedef unsigned int u32;
typedef __attribute__((ext_vector_type(8))) short short8;
typedef __attribute__((ext_vector_type(4))) float floatx4;

#define BMFMA(a, b, c) __builtin_amdgcn_mfma_f32_16x16x32_bf16((a), (b), (c), 0, 0, 0)

__device__ __forceinline__ u16 f2bf(float f) {
  u32 u = __float_as_uint(f);
  u32 r = (u + 0x7FFFu + ((u >> 16) & 1u)) >> 16;  // RNE
  return (u16)r;
}
__device__ __forceinline__ float bflo(u32 u) { return __uint_as_float(u << 16); }
__device__ __forceinline__ float bfhi(u32 u) { return __uint_as_float(u & 0xFFFF0000u); }

__device__ __forceinline__ short8 cvt8(const float4 a, const float4 b) {
  short8 r;
  r[0] = (short)f2bf(a.x); r[1] = (short)f2bf(a.y);
  r[2] = (short)f2bf(a.z); r[3] = (short)f2bf(a.w);
  r[4] = (short)f2bf(b.x); r[5] = (short)f2bf(b.y);
  r[6] = (short)f2bf(b.z); r[7] = (short)f2bf(b.w);
  return r;
}

// ---------------------------------------------------------------------------
// ws layout (u16 element offsets):
//  WeP   @ 0        len 163840  (8 agents x [5kc][8ct][64][8])
//  WsP   @ 163840   len 131072  (8 x 4kc)
//  WkP   @ 294912   len 16384
//  WvP   @ 311296   len 16384
//  WqP   @ 327680   len 16384
//  Wc1P  @ 344064   len 262144  (8 x 8kc)
//  Kbuf  @ 606208   len 33554432   [n][B][128] bf16
//  Vbuf  @ 34160640 len 33554432
//  Qbuf  @ 67715072 len 33554432
//  CI    @ 101269504 len 67108864  [n][B][256] bf16 (s_enc | other)
// ---------------------------------------------------------------------------

__global__ void prep_kernel(const float* __restrict__ We, const float* __restrict__ Ws,
                            const float* __restrict__ Wk, const float* __restrict__ Wq,
                            const float* __restrict__ Wv, const float* __restrict__ Wc1,
                            u16* __restrict__ ws) {
  int idx = blockIdx.x * 256 + threadIdx.x;
  const float* src;
  u16* dst;
  int e, Kreal, mode = 0;
  if (idx < 163840) {
    int a = idx / 20480; e = idx % 20480;
    src = We + a * (IDIM * HID); dst = ws + a * 20480; Kreal = IDIM;
  } else if (idx < 294912) {
    int r = idx - 163840; int a = r >> 14; e = r & 16383;
    src = Ws + a * 16384; dst = ws + 163840 + a * 16384; Kreal = 128;
  } else if (idx < 311296) {
    e = idx - 294912; src = Wk; dst = ws + 294912; Kreal = 128; mode = 1;
  } else if (idx < 327680) {
    e = idx - 311296; src = Wv; dst = ws + 311296; Kreal = 128; mode = 1;
  } else if (idx < 344064) {
    e = idx - 327680; src = Wq; dst = ws + 327680; Kreal = 128; mode = 1;
  } else if (idx < 606208) {
    int r = idx - 344064; int a = r >> 15; e = r & 32767;
    src = Wc1 + a * 32768; dst = ws + 344064 + a * 32768; Kreal = 256;
  } else {
    return;
  }
  int j = e & 7, lane = (e >> 3) & 63, ct = (e >> 9) & 7, kc = e >> 12;
  int k = kc * 32 + ((lane >> 4) << 3) + j;
  int c = ct * 16 + (lane & 15);
  float val = 0.f;
  if (k < Kreal)
    val = mode ? src[((c >> 5) * 128 + k) * 32 + (c & 31)]   // head-combined [H][HID][AD]
               : src[k * 128 + c];
  dst[e] = f2bf(val);
}

// k1 v3: wave-owns-columns. Wave w computes output cols [16w,16w+16) for all
// 128 rows of its (agent, b-tile). B-frags register-resident per phase
// (4-5 short8 = 16-20 VGPR), loaded once, reused across 8 m-subtiles.
// A-frags: inp from global fp32 (L1/L2 reuse across waves); E1/E2 via one
// shared LDS buffer. 3 barriers. LDS 34KB.
//   A-frag: lane l -> A[l&15][kc*32 + (l>>4)*8 + j]
//   C/D:    col = lane&15, row = (lane>>4)*4 + reg
__global__ __launch_bounds__(512, 4) void k1_kernel(
    const float* __restrict__ states, const float* __restrict__ actions,
    const float* __restrict__ be, const float* __restrict__ bs, const float* __restrict__ bv,
    const u16* __restrict__ wsbase,
    u16* __restrict__ Kbuf, u16* __restrict__ Vbuf, u16* __restrict__ Qbuf,
    u16* __restrict__ CI) {
  __shared__ __align__(16) u16 Ebuf[128 * 136];

  const int tid = threadIdx.x, lane = tid & 63, w = tid >> 6;
  const int n = blockIdx.y;
  const size_t b0 = (size_t)blockIdx.x * 128;
  const int cb = lane & 15, qq = lane >> 4;
  const int col = w * 16 + cb;   // this lane's output column
  const int ar = lane & 15;      // A-frag row within 16
  const int koff = qq * 8;       // A-frag k-offset within 32

  const u16* WeF = wsbase + (size_t)n * 20480 + w * 512 + (size_t)lane * 8;
  const u16* WsF = wsbase + 163840 + (size_t)n * 16384 + w * 512 + (size_t)lane * 8;
  const u16* WkF = wsbase + 294912 + w * 512 + (size_t)lane * 8;
  const u16* WvF = wsbase + 311296 + w * 512 + (size_t)lane * 8;
  const u16* WqF = wsbase + 327680 + w * 512 + (size_t)lane * 8;

  const float* Sb = states + ((size_t)n * BB + b0) * SDIM;
  const float* Ab = actions + ((size_t)n * BB + b0) * ADIM;
  const size_t orow = (size_t)n * BB + b0;  // output row base

  floatx4 acc[8];

  // ---- P1: E1 = relu(inp @ We + be) -> Ebuf
  {
    short8 wf[5];
#pragma unroll
    for (int kc = 0; kc < 5; ++kc) wf[kc] = *(const short8*)(WeF + kc * 4096);
#pragma unroll
    for (int m = 0; m < 8; ++m) acc[m] = (floatx4){0.f, 0.f, 0.f, 0.f};
#pragma unroll
    for (int m = 0; m < 8; ++m) {
      const float* sp = Sb + (size_t)(16 * m + ar) * SDIM + koff;
#pragma unroll
      for (int kc = 0; kc < 4; ++kc) {
        float4 x = *(const float4*)(sp + kc * 32);
        float4 y = *(const float4*)(sp + kc * 32 + 4);
        acc[m] = BMFMA(cvt8(x, y), wf[kc], acc[m]);
      }
      short8 af = {0, 0, 0, 0, 0, 0, 0, 0};
      if (qq < 2) {  // koff in {0,8}: actions cols; else zero-pad
        const float* ap = Ab + (size_t)(16 * m + ar) * ADIM + koff;
        float4 x = *(const float4*)ap;
        float4 y = *(const float4*)(ap + 4);
        af = cvt8(x, y);
      }
      acc[m] = BMFMA(af, wf[4], acc[m]);
    }
    const float bb = be[n * HID + col];
#pragma unroll
    for (int m = 0; m < 8; ++m)
#pragma unroll
      for (int r = 0; r < 4; ++r)
        Ebuf[(16 * m + qq * 4 + r) * 136 + col] = f2bf(fmaxf(acc[m][r] + bb, 0.f));
  }
  __syncthreads();  // B1: E1 visible

  // ---- P2: K = E1 @ Wk_all
  {
    short8 wf[4];
#pragma unroll
    for (int kc = 0; kc < 4; ++kc) wf[kc] = *(const short8*)(WkF + kc * 4096);
#pragma unroll
    for (int m = 0; m < 8; ++m) acc[m] = (floatx4){0.f, 0.f, 0.f, 0.f};
#pragma unroll
    for (int m = 0; m < 8; ++m)
#pragma unroll
      for (int kc = 0; kc < 4; ++kc) {
        short8 a = *(const short8*)&Ebuf[(16 * m + ar) * 136 + kc * 32 + koff];
        acc[m] = BMFMA(a, wf[kc], acc[m]);
      }
#pragma unroll
    for (int m = 0; m < 8; ++m)
#pragma unroll
      for (int r = 0; r < 4; ++r)
        Kbuf[(orow + 16 * m + qq * 4 + r) * HID + col] = f2bf(acc[m][r]);
  }

  // ---- P3: V = relu(E1 @ Wv_all + bv)
  {
    short8 wf[4];
#pragma unroll
    for (int kc = 0; kc < 4; ++kc) wf[kc] = *(const short8*)(WvF + kc * 4096);
#pragma unroll
    for (int m = 0; m < 8; ++m) acc[m] = (floatx4){0.f, 0.f, 0.f, 0.f};
#pragma unroll
    for (int m = 0; m < 8; ++m)
#pragma unroll
      for (int kc = 0; kc < 4; ++kc) {
        short8 a = *(const short8*)&Ebuf[(16 * m + ar) * 136 + kc * 32 + koff];
        acc[m] = BMFMA(a, wf[kc], acc[m]);
      }
    const float bb = bv[col];  // bv flat [H][AD] == col index
#pragma unroll
    for (int m = 0; m < 8; ++m)
#pragma unroll
      for (int r = 0; r < 4; ++r)
        Vbuf[(orow + 16 * m + qq * 4 + r) * HID + col] = f2bf(fmaxf(acc[m][r] + bb, 0.f));
  }

  // ---- P4: E2 = relu(states @ Ws + bs); write s_enc -> CI; keep in acc
  {
    short8 wf[4];
#pragma unroll
    for (int kc = 0; kc < 4; ++kc) wf[kc] = *(const short8*)(WsF + kc * 4096);
#pragma unroll
    for (int m = 0; m < 8; ++m) acc[m] = (floatx4){0.f, 0.f, 0.f, 0.f};
#pragma unroll
    for (int m = 0; m < 8; ++m) {
      const float* sp = Sb + (size_t)(16 * m + ar) * SDIM + koff;
#pragma unroll
      for (int kc = 0; kc < 4; ++kc) {
        float4 x = *(const float4*)(sp + kc * 32);
        float4 y = *(const float4*)(sp + kc * 32 + 4);
        acc[m] = BMFMA(cvt8(x, y), wf[kc], acc[m]);
      }
    }
    const float bb = bs[n * HID + col];
#pragma unroll
    for (int m = 0; m < 8; ++m)
#pragma unroll
      for (int r = 0; r < 4; ++r) {
        float v = fmaxf(acc[m][r] + bb, 0.f);
        acc[m][r] = v;
        CI[(orow + 16 * m + qq * 4 + r) * 256 + col] = f2bf(v);
      }
  }
  __syncthreads();  // B2: all waves done reading E1 from Ebuf

  // ---- P5: E2 -> Ebuf
#pragma unroll
  for (int m = 0; m < 8; ++m)
#pragma unroll
    for (int r = 0; r < 4; ++r)
      Ebuf[(16 * m + qq * 4 + r) * 136 + col] = f2bf(acc[m][r]);
  __syncthreads();  // B3: E2 visible

  // ---- P6: Q = E2 @ Wq_all
  {
    short8 wf[4];
#pragma unroll
    for (int kc = 0; kc < 4; ++kc) wf[kc] = *(const short8*)(WqF + kc * 4096);
#pragma unroll
    for (int m = 0; m < 8; ++m) acc[m] = (floatx4){0.f, 0.f, 0.f, 0.f};
#pragma unroll
    for (int m = 0; m < 8; ++m)
#pragma unroll
      for (int kc = 0; kc < 4; ++kc) {
        short8 a = *(const short8*)&Ebuf[(16 * m + ar) * 136 + kc * 32 + koff];
        acc[m] = BMFMA(a, wf[kc], acc[m]);
      }
#pragma unroll
    for (int m = 0; m < 8; ++m)
#pragma unroll
      for (int r = 0; r < 4; ++r)
        Qbuf[(orow + 16 * m + qq * 4 + r) * HID + col] = f2bf(acc[m][r]);
  }
}

// k2: cross-agent attention with LDS-staged K/V (each HBM byte read once).
// Block = 16-b tile. 512 threads: wave = agent i (0..7), lane = h*16 + b.
// LDS layout per buffer: [j:8][b:16] rows of 256B = 16 chunks of 16B;
// chunk t stored at slot (t+b)&15 (rotation swizzle -> even bank-group spread).
__global__ __launch_bounds__(512, 4) void k2_kernel(const u16* __restrict__ Kb,
                                                    const u16* __restrict__ Vb,
                                                    const u16* __restrict__ Qb,
                                                    u16* __restrict__ CI) {
  __shared__ __align__(16) u16 Ksh[8 * 16 * 128];
  __shared__ __align__(16) u16 Vsh[8 * 16 * 128];

  const int tid = threadIdx.x;
  const int i = tid >> 6;          // wave = agent i
  const int lane = tid & 63;
  const int h = lane >> 4;         // head
  const int b = lane & 15;         // b within tile
  const size_t b0 = (size_t)blockIdx.x * 16;
  const float scale = 0.17677669529663687f;  // 1/sqrt(32)

  // ---- stage K and V for this b-tile, all 8 agents
  {
    uint4* kd = (uint4*)Ksh;
    uint4* vd = (uint4*)Vsh;
#pragma unroll
    for (int it = 0; it < 4; ++it) {
      int l = tid + it * 512;
      int j = l >> 8, bs_ = (l >> 4) & 15, t = l & 15;
      size_t gidx = ((size_t)j * BB + b0 + bs_) * 16 + t;  // uint4 units (128 u16 = 16 uint4)
      int slot = (t + bs_) & 15;
      int didx = (j * 16 + bs_) * 16 + slot;
      kd[didx] = ((const uint4*)Kb)[gidx];
      vd[didx] = ((const uint4*)Vb)[gidx];
    }
  }
  __syncthreads();

  // ---- load my Q (exactly once per element globally)
  float q[32];
  {
    const u32* qp = (const u32*)(Qb + ((size_t)i * BB + b0 + b) * HID + h * 32);
#pragma unroll
    for (int t = 0; t < 16; ++t) {
      u32 u = qp[t];
      q[2 * t] = bflo(u);
      q[2 * t + 1] = bfhi(u);
    }
  }

  // ---- logits
  float lg[8];
#pragma unroll
  for (int j = 0; j < 8; ++j) {
    if (j != i) {  // wave-uniform branch (i is per-wave constant)
      float acc = 0.f;
#pragma unroll
      for (int c = 0; c < 4; ++c) {
        int slot = ((h * 4 + c) + b) & 15;
        uint4 kv = *(const uint4*)&Ksh[((j * 16 + b) * 16 + slot) * 8];
        const u32 kw[4] = {kv.x, kv.y, kv.z, kv.w};
#pragma unroll
        for (int t = 0; t < 4; ++t) {
          int d = c * 8 + t * 2;
          acc = fmaf(bflo(kw[t]), q[d], acc);
          acc = fmaf(bfhi(kw[t]), q[d + 1], acc);
        }
      }
      lg[j] = acc * scale;
    } else {
      lg[j] = -1e9f;  // exact reference masking
    }
  }

  // ---- softmax (matches reference: max includes the -1e9 entry)
  float m = lg[0];
#pragma unroll
  for (int j = 1; j < 8; ++j) m = fmaxf(m, lg[j]);
  float p[8], s = 0.f;
#pragma unroll
  for (int j = 0; j < 8; ++j) {
    p[j] = __expf(lg[j] - m);
    s += p[j];
  }
  const float inv = 1.f / s;

  // ---- o = attn @ V
  float o[32];
#pragma unroll
  for (int d = 0; d < 32; ++d) o[d] = 0.f;
#pragma unroll
  for (int j = 0; j < 8; ++j) {
    if (j == i) continue;
    const float pj = p[j] * inv;
#pragma unroll
    for (int c = 0; c < 4; ++c) {
      int slot = ((h * 4 + c) + b) & 15;
      uint4 vv = *(const uint4*)&Vsh[((j * 16 + b) * 16 + slot) * 8];
      const u32 vw[4] = {vv.x, vv.y, vv.z, vv.w};
#pragma unroll
      for (int t = 0; t < 4; ++t) {
        int d = c * 8 + t * 2;
        o[d] = fmaf(pj, bflo(vw[t]), o[d]);
        o[d + 1] = fmaf(pj, bfhi(vw[t]), o[d + 1]);
      }
    }
  }

  // ---- pack & write `other`
  u32 ow[16];
#pragma unroll
  for (int t = 0; t < 16; ++t)
    ow[t] = (u32)f2bf(o[2 * t]) | ((u32)f2bf(o[2 * t + 1]) << 16);
  uint4* op = (uint4*)(CI + ((size_t)i * BB + b0 + b) * 256 + 128 + h * 32);
  op[0] = make_uint4(ow[0], ow[1], ow[2], ow[3]);
  op[1] = make_uint4(ow[4], ow[5], ow[6], ow[7]);
  op[2] = make_uint4(ow[8], ow[9], ow[10], ow[11]);
  op[3] = make_uint4(ow[12], ow[13], ow[14], ow[15]);
}

// k3 v3: critic. Wave-owns-columns with register-resident Wc1 frags (8 short8).
// A staged once in LDS (stride 264). h1 -> Alds (stride 136) -> gather-dot.
__global__ __launch_bounds__(512, 4) void k3_kernel(
    const u16* __restrict__ CI, const u16* __restrict__ Wc1P, const float* __restrict__ bc1,
    const float* __restrict__ Wc2, const float* __restrict__ bc2,
    const float* __restrict__ actions, float* __restrict__ out) {
  __shared__ __align__(16) u16 Alds[128 * 264];  // A tile; later reused for H1 (stride 136)
  __shared__ __align__(16) float Wc2s[2048];

  const int tid = threadIdx.x, lane = tid & 63, w = tid >> 6;
  const int n = blockIdx.y;
  const size_t b0 = (size_t)blockIdx.x * 128;
  const int cb = lane & 15, qq = lane >> 4;
  const int col = w * 16 + cb;
  const int ar = lane & 15;
  const int koff = qq * 8;

  {
    const uint4* src = (const uint4*)(CI + ((size_t)n * BB + b0) * 256);
    uint4* dstA = (uint4*)Alds;
#pragma unroll
    for (int it = 0; it < 8; ++it) {
      int c = tid + it * 512;
      int row = c >> 5, c16 = c & 31;
      dstA[row * 33 + c16] = src[c];  // LDS row stride = 264 u16 = 33 uint4
    }
    ((float4*)Wc2s)[tid] = ((const float4*)(Wc2 + n * 2048))[tid];
  }
  __syncthreads();

  floatx4 acc[8];
  {
    const u16* WcF = Wc1P + (size_t)n * 32768 + w * 512 + (size_t)lane * 8;
    short8 wf[8];
#pragma unroll
    for (int kc = 0; kc < 8; ++kc) wf[kc] = *(const short8*)(WcF + kc * 4096);
#pragma unroll
    for (int m = 0; m < 8; ++m) acc[m] = (floatx4){0.f, 0.f, 0.f, 0.f};
#pragma unroll
    for (int m = 0; m < 8; ++m)
#pragma unroll
      for (int kc = 0; kc < 8; ++kc) {
        short8 a = *(const short8*)&Alds[(16 * m + ar) * 264 + kc * 32 + koff];
        acc[m] = BMFMA(a, wf[kc], acc[m]);
      }
  }
  __syncthreads();  // everyone done reading A before H1 overwrites it

  {
    const float bb = bc1[n * HID + col];
#pragma unroll
    for (int m = 0; m < 8; ++m)
#pragma unroll
      for (int r = 0; r < 4; ++r)
        Alds[(16 * m + qq * 4 + r) * 136 + col] = f2bf(fmaxf(acc[m][r] + bb, 0.f));
  }
  __syncthreads();

  {
    const int bloc = tid >> 2, part = tid & 3;
    const size_t b = b0 + bloc;
    const float* ap = actions + ((size_t)n * BB + b) * ADIM;
    int am = 0;
    float mv = ap[0];
#pragma unroll
    for (int t = 1; t < 16; ++t) {
      float v = ap[t];
      if (v > mv) { mv = v; am = t; }  // strict > keeps first max (argmax semantics)
    }
    float a2 = 0.f;
    const int cbk = part * 32;
#pragma unroll
    for (int c2 = 0; c2 < 32; ++c2) {
      float hv = __uint_as_float((u32)Alds[bloc * 136 + cbk + c2] << 16);
      a2 = fmaf(hv, Wc2s[(cbk + c2) * 16 + am], a2);
    }
    a2 += __shfl_xor(a2, 1);
    a2 += __shfl_xor(a2, 2);
    if (part == 0) out[(size_t)n * BB + b] = a2 + bc2[n * ADIM + am];
  }
}

extern "C" void kernel_launch(void* const* d_in, const int* in_sizes, int n_in,
                              void* d_out, int out_size, void* d_ws, size_t ws_size,
                              hipStream_t stream) {
  const float* states  = (const float*)d_in[0];
  const float* actions = (const float*)d_in[1];
  const float* We  = (const float*)d_in[2];
  const float* be  = (const float*)d_in[3];
  const float* Ws  = (const float*)d_in[4];
  const float* bs  = (const float*)d_in[5];
  const float* Wk  = (const float*)d_in[6];
  const float* Wq  = (const float*)d_in[7];
  const float* Wv  = (const float*)d_in[8];
  const float* bv  = (const float*)d_in[9];
  const float* Wc1 = (const float*)d_in[10];
  const float* bc1 = (const float*)d_in[11];
  const float* Wc2 = (const float*)d_in[12];
  const float* bc2 = (const float*)d_in[13];
  float* out = (float*)d_out;
  u16* ws = (u16*)d_ws;

  u16* Kbuf = ws + 606208;
  u16* Vbuf = ws + 34160640;
  u16* Qbuf = ws + 67715072;
  u16* CI   = ws + 101269504;

  prep_kernel<<<2368, 256, 0, stream>>>(We, Ws, Wk, Wq, Wv, Wc1, ws);
  k1_kernel<<<dim3(256, 8), 512, 0, stream>>>(states, actions, be, bs, bv, ws,
                                              Kbuf, Vbuf, Qbuf, CI);
  k2_kernel<<<2048, 512, 0, stream>>>(Kbuf, Vbuf, Qbuf, CI);
  k3_kernel<<<dim3(256, 8), 512, 0, stream>>>(CI, ws + 344064, bc1, Wc2, bc2, actions, out);
}

// Round 5
// 420.321 us; speedup vs baseline: 1.5358x; 1.5358x over previous
//
#include <hip/hip_runtime.h>

// Problem constants
#define NAG 8
#define BB 32768
#define SDIM 128
#define ADIM 16
#define HID 128
#define IDIM 144

typedef unsigned short u16;
typedef unsigned int u32;
typedef __attribute__((ext_vector_type(8))) short short8;
typedef __attribute__((ext_vector_type(4))) float floatx4;

#define BMFMA(a, b, c) __builtin_amdgcn_mfma_f32_16x16x32_bf16((a), (b), (c), 0, 0, 0)

__device__ __forceinline__ u16 f2bf(float f) {
  u32 u = __float_as_uint(f);
  u32 r = (u + 0x7FFFu + ((u >> 16) & 1u)) >> 16;  // RNE
  return (u16)r;
}
__device__ __forceinline__ float bflo(u32 u) { return __uint_as_float(u << 16); }
__device__ __forceinline__ float bfhi(u32 u) { return __uint_as_float(u & 0xFFFF0000u); }

__device__ __forceinline__ short8 cvt8(const float4 a, const float4 b) {
  short8 r;
  r[0] = (short)f2bf(a.x); r[1] = (short)f2bf(a.y);
  r[2] = (short)f2bf(a.z); r[3] = (short)f2bf(a.w);
  r[4] = (short)f2bf(b.x); r[5] = (short)f2bf(b.y);
  r[6] = (short)f2bf(b.z); r[7] = (short)f2bf(b.w);
  return r;
}
__device__ __forceinline__ uint2 pack4(float a, float b, float c, float d) {
  return make_uint2((u32)f2bf(a) | ((u32)f2bf(b) << 16),
                    (u32)f2bf(c) | ((u32)f2bf(d) << 16));
}

__device__ __forceinline__ void stageW(u16* Wb, const u16* __restrict__ src, int nu4, int tid) {
  const uint4* s4 = (const uint4*)src;
  uint4* d4 = (uint4*)Wb;
#pragma unroll 1
  for (int it = tid; it < nu4; it += 512) d4[it] = s4[it];
}

// ---------------------------------------------------------------------------
// ws layout (u16 element offsets):
//  WeP   @ 0        len 163840  (8 agents x [5kc][8ct][64][8])
//  WsP   @ 163840   len 131072  (8 x 4kc)
//  WkP   @ 294912   len 16384
//  WvP   @ 311296   len 16384
//  WqP   @ 327680   len 16384
//  Wc1P  @ 344064   len 262144  (8 x 8kc)
//  Kbuf  @ 606208   len 33554432   [n][B][128] bf16
//  Vbuf  @ 34160640 len 33554432
//  Qbuf  @ 67715072 len 33554432
//  CI    @ 101269504 len 67108864  [n][B][256] bf16 (s_enc | other)
// ---------------------------------------------------------------------------
// Frag layout (serves BOTH as B-frag of W and A-frag of W^T — identical):
//   frag[(kc*8+ct)*512 + lane*8 + j] = W[kc*32+(lane>>4)*8+j][ct*16+(lane&15)]

__global__ void prep_kernel(const float* __restrict__ We, const float* __restrict__ Ws,
                            const float* __restrict__ Wk, const float* __restrict__ Wq,
                            const float* __restrict__ Wv, const float* __restrict__ Wc1,
                            u16* __restrict__ ws) {
  int idx = blockIdx.x * 256 + threadIdx.x;
  const float* src;
  u16* dst;
  int e, Kreal, mode = 0;
  if (idx < 163840) {
    int a = idx / 20480; e = idx % 20480;
    src = We + a * (IDIM * HID); dst = ws + a * 20480; Kreal = IDIM;
  } else if (idx < 294912) {
    int r = idx - 163840; int a = r >> 14; e = r & 16383;
    src = Ws + a * 16384; dst = ws + 163840 + a * 16384; Kreal = 128;
  } else if (idx < 311296) {
    e = idx - 294912; src = Wk; dst = ws + 294912; Kreal = 128; mode = 1;
  } else if (idx < 327680) {
    e = idx - 311296; src = Wv; dst = ws + 311296; Kreal = 128; mode = 1;
  } else if (idx < 344064) {
    e = idx - 327680; src = Wq; dst = ws + 327680; Kreal = 128; mode = 1;
  } else if (idx < 606208) {
    int r = idx - 344064; int a = r >> 15; e = r & 32767;
    src = Wc1 + a * 32768; dst = ws + 344064 + a * 32768; Kreal = 256;
  } else {
    return;
  }
  int j = e & 7, lane = (e >> 3) & 63, ct = (e >> 9) & 7, kc = e >> 12;
  int k = kc * 32 + ((lane >> 4) << 3) + j;
  int c = ct * 16 + (lane & 15);
  float val = 0.f;
  if (k < Kreal)
    val = mode ? src[((c >> 5) * 128 + k) * 32 + (c & 31)]   // head-combined [H][HID][AD]
               : src[k * 128 + c];
  dst[e] = f2bf(val);
}

// k1 v5: transposed MFMA. Wave w owns b-rows [w*16, w*16+16). Per phase:
//   A-operand = W^T frags from LDS (staged once per phase, shared),
//   B-operand = inp^T / E^T frags in REGISTERS (loaded once per phase),
//   D: lane(qq,cb) holds Out[b = cb][cols ct*16+qq*4 .. +4] -> uint2 stores,
//      wave writes FULL 256B output rows (L2 line assembly, no write amp).
// E1/E2 bounce via wave-local LDS stash (no barriers). 9 barriers total.
// LDS 40KB (Wb) + 34KB (stash) = 74KB -> 2 blocks/CU.
__global__ __launch_bounds__(512, 4) void k1_kernel(
    const float* __restrict__ states, const float* __restrict__ actions,
    const float* __restrict__ be, const float* __restrict__ bs, const float* __restrict__ bv,
    const u16* __restrict__ wsbase,
    u16* __restrict__ Kbuf, u16* __restrict__ Vbuf, u16* __restrict__ Qbuf,
    u16* __restrict__ CI) {
  __shared__ __align__(16) u16 Wb[20480];        // weight frags for current phase
  __shared__ __align__(16) u16 Est[8 * 16 * 136];  // per-wave E stash [16 b][136]

  const int tid = threadIdx.x, lane = tid & 63, w = tid >> 6;
  const int cb = lane & 15, qq = lane >> 4;
  const int n = blockIdx.y;
  const size_t b0 = (size_t)blockIdx.x * 128;
  const size_t grow = (size_t)n * BB + b0 + w * 16 + cb;  // this lane's global row
  u16* stw = Est + w * (16 * 136) + cb * 136;             // wave-local stash row

  const u16* WeP = wsbase + (size_t)n * 20480;
  const u16* WsP = wsbase + 163840 + (size_t)n * 16384;
  const u16* WkP = wsbase + 294912;
  const u16* WvP = wsbase + 311296;
  const u16* WqP = wsbase + 327680;

  // ---- P1: E1 = relu(inp @ We + be) -> stash
  stageW(Wb, WeP, 2560, tid);
  // load inp^T B-frags into registers (lane reads its own row cb, k = kc*32+qq*8)
  short8 xf[5];
  {
    const float* sp = states + grow * SDIM + qq * 8;
#pragma unroll
    for (int kc = 0; kc < 4; ++kc) {
      float4 x = *(const float4*)(sp + kc * 32);
      float4 y = *(const float4*)(sp + kc * 32 + 4);
      xf[kc] = cvt8(x, y);
    }
    xf[4] = (short8){0, 0, 0, 0, 0, 0, 0, 0};
    if (qq < 2) {  // k in [128,144): actions; k in [144,160): zero pad
      const float* ap = actions + grow * ADIM + qq * 8;
      xf[4] = cvt8(*(const float4*)ap, *(const float4*)(ap + 4));
    }
  }
  __syncthreads();  // Wb=We ready
#pragma unroll
  for (int ct = 0; ct < 8; ++ct) {
    floatx4 a = (floatx4){0.f, 0.f, 0.f, 0.f};
#pragma unroll
    for (int kc = 0; kc < 5; ++kc) {
      short8 wfr = *(const short8*)&Wb[(kc * 8 + ct) * 512 + lane * 8];
      a = BMFMA(wfr, xf[kc], a);
    }
    floatx4 bb = *(const floatx4*)&be[n * HID + ct * 16 + qq * 4];
    *(uint2*)&stw[ct * 16 + qq * 4] =
        pack4(fmaxf(a[0] + bb[0], 0.f), fmaxf(a[1] + bb[1], 0.f),
              fmaxf(a[2] + bb[2], 0.f), fmaxf(a[3] + bb[3], 0.f));
  }
  __syncthreads();  // all waves done reading Wb=We

  // ---- P2: K = E1 @ Wk
  stageW(Wb, WkP, 2048, tid);
  short8 ef[4];
#pragma unroll
  for (int kc = 0; kc < 4; ++kc) ef[kc] = *(const short8*)&stw[kc * 32 + qq * 8];
  __syncthreads();  // Wb=Wk ready
#pragma unroll
  for (int ct = 0; ct < 8; ++ct) {
    floatx4 a = (floatx4){0.f, 0.f, 0.f, 0.f};
#pragma unroll
    for (int kc = 0; kc < 4; ++kc) {
      short8 wfr = *(const short8*)&Wb[(kc * 8 + ct) * 512 + lane * 8];
      a = BMFMA(wfr, ef[kc], a);
    }
    *(uint2*)&Kbuf[grow * HID + ct * 16 + qq * 4] = pack4(a[0], a[1], a[2], a[3]);
  }
  __syncthreads();

  // ---- P3: V = relu(E1 @ Wv + bv)   (ef regs still hold E1)
  stageW(Wb, WvP, 2048, tid);
  __syncthreads();
#pragma unroll
  for (int ct = 0; ct < 8; ++ct) {
    floatx4 a = (floatx4){0.f, 0.f, 0.f, 0.f};
#pragma unroll
    for (int kc = 0; kc < 4; ++kc) {
      short8 wfr = *(const short8*)&Wb[(kc * 8 + ct) * 512 + lane * 8];
      a = BMFMA(wfr, ef[kc], a);
    }
    floatx4 bb = *(const floatx4*)&bv[ct * 16 + qq * 4];  // bv flat [H][AD] == col
    *(uint2*)&Vbuf[grow * HID + ct * 16 + qq * 4] =
        pack4(fmaxf(a[0] + bb[0], 0.f), fmaxf(a[1] + bb[1], 0.f),
              fmaxf(a[2] + bb[2], 0.f), fmaxf(a[3] + bb[3], 0.f));
  }
  __syncthreads();

  // ---- P4: E2 = relu(states @ Ws + bs) -> CI[:,0:128] and stash (overwrite)
  stageW(Wb, WsP, 2048, tid);
  __syncthreads();
#pragma unroll
  for (int ct = 0; ct < 8; ++ct) {
    floatx4 a = (floatx4){0.f, 0.f, 0.f, 0.f};
#pragma unroll
    for (int kc = 0; kc < 4; ++kc) {
      short8 wfr = *(const short8*)&Wb[(kc * 8 + ct) * 512 + lane * 8];
      a = BMFMA(wfr, xf[kc], a);
    }
    floatx4 bb = *(const floatx4*)&bs[n * HID + ct * 16 + qq * 4];
    uint2 pk = pack4(fmaxf(a[0] + bb[0], 0.f), fmaxf(a[1] + bb[1], 0.f),
                     fmaxf(a[2] + bb[2], 0.f), fmaxf(a[3] + bb[3], 0.f));
    *(uint2*)&CI[grow * 256 + ct * 16 + qq * 4] = pk;   // s_enc half
    *(uint2*)&stw[ct * 16 + qq * 4] = pk;               // wave-local: safe, E1 consumed
  }
  __syncthreads();

  // ---- P5: Q = E2 @ Wq
  stageW(Wb, WqP, 2048, tid);
#pragma unroll
  for (int kc = 0; kc < 4; ++kc) ef[kc] = *(const short8*)&stw[kc * 32 + qq * 8];
  __syncthreads();
#pragma unroll
  for (int ct = 0; ct < 8; ++ct) {
    floatx4 a = (floatx4){0.f, 0.f, 0.f, 0.f};
#pragma unroll
    for (int kc = 0; kc < 4; ++kc) {
      short8 wfr = *(const short8*)&Wb[(kc * 8 + ct) * 512 + lane * 8];
      a = BMFMA(wfr, ef[kc], a);
    }
    *(uint2*)&Qbuf[grow * HID + ct * 16 + qq * 4] = pack4(a[0], a[1], a[2], a[3]);
  }
}

// k2: cross-agent attention with LDS-staged K/V (each HBM byte read once).
// Block = 16-b tile. 512 threads: wave = agent i (0..7), lane = h*16 + b.
__global__ __launch_bounds__(512, 4) void k2_kernel(const u16* __restrict__ Kb,
                                                    const u16* __restrict__ Vb,
                                                    const u16* __restrict__ Qb,
                                                    u16* __restrict__ CI) {
  __shared__ __align__(16) u16 Ksh[8 * 16 * 128];
  __shared__ __align__(16) u16 Vsh[8 * 16 * 128];

  const int tid = threadIdx.x;
  const int i = tid >> 6;          // wave = agent i
  const int lane = tid & 63;
  const int h = lane >> 4;         // head
  const int b = lane & 15;         // b within tile
  const size_t b0 = (size_t)blockIdx.x * 16;
  const float scale = 0.17677669529663687f;  // 1/sqrt(32)

  {
    uint4* kd = (uint4*)Ksh;
    uint4* vd = (uint4*)Vsh;
#pragma unroll
    for (int it = 0; it < 4; ++it) {
      int l = tid + it * 512;
      int j = l >> 8, bs_ = (l >> 4) & 15, t = l & 15;
      size_t gidx = ((size_t)j * BB + b0 + bs_) * 16 + t;
      int slot = (t + bs_) & 15;
      int didx = (j * 16 + bs_) * 16 + slot;
      kd[didx] = ((const uint4*)Kb)[gidx];
      vd[didx] = ((const uint4*)Vb)[gidx];
    }
  }
  __syncthreads();

  float q[32];
  {
    const u32* qp = (const u32*)(Qb + ((size_t)i * BB + b0 + b) * HID + h * 32);
#pragma unroll
    for (int t = 0; t < 16; ++t) {
      u32 u = qp[t];
      q[2 * t] = bflo(u);
      q[2 * t + 1] = bfhi(u);
    }
  }

  float lg[8];
#pragma unroll
  for (int j = 0; j < 8; ++j) {
    if (j != i) {
      float acc = 0.f;
#pragma unroll
      for (int c = 0; c < 4; ++c) {
        int slot = ((h * 4 + c) + b) & 15;
        uint4 kv = *(const uint4*)&Ksh[((j * 16 + b) * 16 + slot) * 8];
        const u32 kw[4] = {kv.x, kv.y, kv.z, kv.w};
#pragma unroll
        for (int t = 0; t < 4; ++t) {
          int d = c * 8 + t * 2;
          acc = fmaf(bflo(kw[t]), q[d], acc);
          acc = fmaf(bfhi(kw[t]), q[d + 1], acc);
        }
      }
      lg[j] = acc * scale;
    } else {
      lg[j] = -1e9f;  // exact reference masking
    }
  }

  float m = lg[0];
#pragma unroll
  for (int j = 1; j < 8; ++j) m = fmaxf(m, lg[j]);
  float p[8], s = 0.f;
#pragma unroll
  for (int j = 0; j < 8; ++j) {
    p[j] = __expf(lg[j] - m);
    s += p[j];
  }
  const float inv = 1.f / s;

  float o[32];
#pragma unroll
  for (int d = 0; d < 32; ++d) o[d] = 0.f;
#pragma unroll
  for (int j = 0; j < 8; ++j) {
    if (j == i) continue;
    const float pj = p[j] * inv;
#pragma unroll
    for (int c = 0; c < 4; ++c) {
      int slot = ((h * 4 + c) + b) & 15;
      uint4 vv = *(const uint4*)&Vsh[((j * 16 + b) * 16 + slot) * 8];
      const u32 vw[4] = {vv.x, vv.y, vv.z, vv.w};
#pragma unroll
      for (int t = 0; t < 4; ++t) {
        int d = c * 8 + t * 2;
        o[d] = fmaf(pj, bflo(vw[t]), o[d]);
        o[d + 1] = fmaf(pj, bfhi(vw[t]), o[d + 1]);
      }
    }
  }

  u32 ow[16];
#pragma unroll
  for (int t = 0; t < 16; ++t)
    ow[t] = (u32)f2bf(o[2 * t]) | ((u32)f2bf(o[2 * t + 1]) << 16);
  uint4* op = (uint4*)(CI + ((size_t)i * BB + b0 + b) * 256 + 128 + h * 32);
  op[0] = make_uint4(ow[0], ow[1], ow[2], ow[3]);
  op[1] = make_uint4(ow[4], ow[5], ow[6], ow[7]);
  op[2] = make_uint4(ow[8], ow[9], ow[10], ow[11]);
  op[3] = make_uint4(ow[12], ow[13], ow[14], ow[15]);
}

// k3 v5: transposed MFMA critic. Wave owns 16 b's; CI^T B-frags from global
// into regs; Wc1^T A-frags from LDS (staged in two 32KB halves); h1 stays in
// registers; gather-dot + 4-lane reduce. LDS 40KB -> 4 blocks/CU. 3 barriers.
__global__ __launch_bounds__(512, 4) void k3_kernel(
    const u16* __restrict__ CI, const u16* __restrict__ Wc1P, const float* __restrict__ bc1,
    const float* __restrict__ Wc2, const float* __restrict__ bc2,
    const float* __restrict__ actions, float* __restrict__ out) {
  __shared__ __align__(16) u16 Wb[16384];     // 4 kc slabs of Wc1 frags
  __shared__ __align__(16) float Wc2s[2048];

  const int tid = threadIdx.x, lane = tid & 63, w = tid >> 6;
  const int cb = lane & 15, qq = lane >> 4;
  const int n = blockIdx.y;
  const size_t b0 = (size_t)blockIdx.x * 128;
  const size_t grow = (size_t)n * BB + b0 + w * 16 + cb;

  const u16* W1 = Wc1P + (size_t)n * 32768;
  Wc2s[tid] = Wc2[n * 2048 + tid];
  Wc2s[tid + 512] = Wc2[n * 2048 + tid + 512];
  Wc2s[tid + 1024] = Wc2[n * 2048 + tid + 1024];
  Wc2s[tid + 1536] = Wc2[n * 2048 + tid + 1536];
  stageW(Wb, W1, 2048, tid);

  const u16* cip = CI + grow * 256;
  short8 cf[4];
#pragma unroll
  for (int kc = 0; kc < 4; ++kc) cf[kc] = *(const short8*)(cip + kc * 32 + qq * 8);

  floatx4 acc[8];
#pragma unroll
  for (int ct = 0; ct < 8; ++ct) acc[ct] = (floatx4){0.f, 0.f, 0.f, 0.f};

  __syncthreads();  // Wb half1 + Wc2s ready
#pragma unroll
  for (int ct = 0; ct < 8; ++ct)
#pragma unroll
    for (int kc = 0; kc < 4; ++kc) {
      short8 wfr = *(const short8*)&Wb[(kc * 8 + ct) * 512 + lane * 8];
      acc[ct] = BMFMA(wfr, cf[kc], acc[ct]);
    }
  __syncthreads();  // done reading half1
  stageW(Wb, W1 + 16384, 2048, tid);
#pragma unroll
  for (int kc = 0; kc < 4; ++kc) cf[kc] = *(const short8*)(cip + 128 + kc * 32 + qq * 8);
  __syncthreads();  // Wb half2 ready
#pragma unroll
  for (int ct = 0; ct < 8; ++ct)
#pragma unroll
    for (int kc = 0; kc < 4; ++kc) {
      short8 wfr = *(const short8*)&Wb[(kc * 8 + ct) * 512 + lane * 8];
      acc[ct] = BMFMA(wfr, cf[kc], acc[ct]);
    }

  // argmax(actions[row]) — strict > keeps first max
  const float* ap = actions + grow * ADIM;
  int am = 0;
  float mv = ap[0];
#pragma unroll
  for (int t = 1; t < 16; ++t) {
    float v = ap[t];
    if (v > mv) { mv = v; am = t; }
  }

  // h1 = relu(acc + bc1) in regs; dot with Wc2[:, am]
  float a2 = 0.f;
#pragma unroll
  for (int ct = 0; ct < 8; ++ct) {
    floatx4 bb = *(const floatx4*)&bc1[n * HID + ct * 16 + qq * 4];
#pragma unroll
    for (int r = 0; r < 4; ++r) {
      float h = fmaxf(acc[ct][r] + bb[r], 0.f);
      a2 = fmaf(h, Wc2s[(ct * 16 + qq * 4 + r) * 16 + am], a2);
    }
  }
  a2 += __shfl_xor(a2, 16);
  a2 += __shfl_xor(a2, 32);
  if (qq == 0) out[grow] = a2 + bc2[n * ADIM + am];
}

extern "C" void kernel_launch(void* const* d_in, const int* in_sizes, int n_in,
                              void* d_out, int out_size, void* d_ws, size_t ws_size,
                              hipStream_t stream) {
  const float* states  = (const float*)d_in[0];
  const float* actions = (const float*)d_in[1];
  const float* We  = (const float*)d_in[2];
  const float* be  = (const float*)d_in[3];
  const float* Ws  = (const float*)d_in[4];
  const float* bs  = (const float*)d_in[5];
  const float* Wk  = (const float*)d_in[6];
  const float* Wq  = (const float*)d_in[7];
  const float* Wv  = (const float*)d_in[8];
  const float* bv  = (const float*)d_in[9];
  const float* Wc1 = (const float*)d_in[10];
  const float* bc1 = (const float*)d_in[11];
  const float* Wc2 = (const float*)d_in[12];
  const float* bc2 = (const float*)d_in[13];
  float* out = (float*)d_out;
  u16* ws = (u16*)d_ws;

  u16* Kbuf = ws + 606208;
  u16* Vbuf = ws + 34160640;
  u16* Qbuf = ws + 67715072;
  u16* CI   = ws + 101269504;

  prep_kernel<<<2368, 256, 0, stream>>>(We, Ws, Wk, Wq, Wv, Wc1, ws);
  k1_kernel<<<dim3(256, 8), 512, 0, stream>>>(states, actions, be, bs, bv, ws,
                                              Kbuf, Vbuf, Qbuf, CI);
  k2_kernel<<<2048, 512, 0, stream>>>(Kbuf, Vbuf, Qbuf, CI);
  k3_kernel<<<dim3(256, 8), 512, 0, stream>>>(CI, ws + 344064, bc1, Wc2, bc2, actions, out);
}